// Round 6
// baseline (298.038 us; speedup 1.0000x reference)
//
#include <hip/hip_runtime.h>
#include <hip/hip_bf16.h>
#include <hip/hip_cooperative_groups.h>
#include <stdint.h>

namespace cg = cooperative_groups;

#define ALPHA 0.2f

typedef __attribute__((ext_vector_type(8))) short bf16x8;
typedef __attribute__((ext_vector_type(4))) float f32x4;

__device__ __forceinline__ short f2bf(float f) {
    union { float f; uint32_t u; } c; c.f = f;
    uint32_t u = c.u + 0x7FFF + ((c.u >> 16) & 1);   // round-to-nearest-even
    return (short)(u >> 16);
}

// pack two fp32 -> packed bf16 pair (round-half-up)
__device__ __forceinline__ uint32_t pk_bf16(float lo, float hi) {
    union { float f; uint32_t u; } a, b;
    a.f = lo; b.f = hi;
    return __builtin_amdgcn_perm(b.u + 0x8000u, a.u + 0x8000u, 0x07060302u);
}

// async global->LDS, 16 B per lane. l must be wave-uniform; g is per-lane.
__device__ __forceinline__ void gload_lds16(const void* g, void* l) {
    __builtin_amdgcn_global_load_lds(
        (const __attribute__((address_space(1))) void*)g,
        (__attribute__((address_space(3))) void*)l, 16, 0, 0);
}

// ---------------------------------------------------------------------------
// Fused cooperative kernel: phase 0 (pack adj + WT) -> grid.sync ->
// phase 1 (Wh GEMM + s1/s2 + whT chunk layout) -> grid.sync ->
// phase 2 (masked-softmax attention + PV, v16 structure).
// Grid 512 x 256, LDS 49.5 KB -> exactly 2 blocks/CU co-resident (required
// for cooperative launch; 512 = 256 CU x 2). Same blockIdx&7 batch<->XCD
// mapping in phases 1 and 2 keeps whT/s1/s2 XCD-local and L2-hot.
// Removes two kernel-boundary full-drains + dispatch overheads.
// ---------------------------------------------------------------------------
__global__ __launch_bounds__(256, 2) void fused_kernel(
        const float* __restrict__ h, const int* __restrict__ adj,
        const float* __restrict__ W, const float* __restrict__ a,
        short* __restrict__ whT, float* __restrict__ s1g,
        float* __restrict__ s2g, uint8_t* __restrict__ adjb,
        short* __restrict__ WTg, float* __restrict__ out) {

    __shared__ __align__(16) char smem[49536];       // union of all phases

    int tid = threadIdx.x, wid = tid >> 6, lane = tid & 63;
    int q = lane >> 4, n = lane & 15;
    cg::grid_group grid = cg::this_grid();

    // =======================================================================
    // Phase 0: pack adj into byte masks (4 passes) + transpose W -> bf16 WTg
    // =======================================================================
    {
        int gtid = blockIdx.x * 256 + tid;           // 131072 threads
        #pragma unroll
        for (int pass = 0; pass < 4; ++pass) {
            int t = pass * 131072 + gtid;
            const int4* a4 = reinterpret_cast<const int4*>(adj) + (size_t)t * 2;
            int4 x0 = a4[0], x1 = a4[1];
            uint32_t m = 0;
            m |= (x0.x > 0) ? 1u   : 0u;  m |= (x0.y > 0) ? 2u   : 0u;
            m |= (x0.z > 0) ? 4u   : 0u;  m |= (x0.w > 0) ? 8u   : 0u;
            m |= (x1.x > 0) ? 16u  : 0u;  m |= (x1.y > 0) ? 32u  : 0u;
            m |= (x1.z > 0) ? 64u  : 0u;  m |= (x1.w > 0) ? 128u : 0u;
            adjb[t] = (uint8_t)m;
        }
        if (blockIdx.x < 64) {
            int idx = blockIdx.x * 256 + tid;
            int k = idx >> 7, f = idx & 127;
            WTg[f * 128 + k] = f2bf(W[k * 128 + f]);
        }
    }

    __threadfence();
    grid.sync();

    // =======================================================================
    // Phase 1: Wh = h @ W (bf16 MFMA); s1/s2 (pre-scaled by log2 e) and whT
    // in MFMA-frag-ordered chunk layout. 2 row-tiles of 16 per block.
    // =======================================================================
    {
        float (*sred)[2][16] = reinterpret_cast<float (*)[2][16]>(smem);     // 512 B
        short (*tr)[32][24]  = reinterpret_cast<short (*)[32][24]>(smem + 512); // 6 KB

        int bb = blockIdx.x & 7;                     // XCD-local batch
        int tile0 = blockIdx.x >> 3;                 // 0..63
        #pragma unroll
        for (int t2 = 0; t2 < 2; ++t2) {
            if (t2) __syncthreads();                 // sred/tr reuse hazard
            int tile = tile0 + t2 * 64;              // 0..127
            int rb = bb * 2048 + tile * 16;
            int row = rb + n;

            f32x4 acc[2] = {};
            #pragma unroll
            for (int kc = 0; kc < 4; ++kc) {
                const float* hp = h + (size_t)row * 128 + kc * 32 + q * 8;
                float4 h0 = reinterpret_cast<const float4*>(hp)[0];
                float4 h1 = reinterpret_cast<const float4*>(hp)[1];
                bf16x8 afrag;
                afrag[0] = f2bf(h0.x); afrag[1] = f2bf(h0.y);
                afrag[2] = f2bf(h0.z); afrag[3] = f2bf(h0.w);
                afrag[4] = f2bf(h1.x); afrag[5] = f2bf(h1.y);
                afrag[6] = f2bf(h1.z); afrag[7] = f2bf(h1.w);
                #pragma unroll
                for (int u = 0; u < 2; ++u) {
                    int t = wid * 2 + u;
                    bf16x8 bfrag = *reinterpret_cast<const bf16x8*>(
                        WTg + (t * 16 + n) * 128 + kc * 32 + q * 8);
                    acc[u] = __builtin_amdgcn_mfma_f32_16x16x32_bf16(afrag, bfrag, acc[u], 0, 0, 0);
                }
            }

            float p1[4] = {0.f, 0.f, 0.f, 0.f}, p2[4] = {0.f, 0.f, 0.f, 0.f};
            #pragma unroll
            for (int u = 0; u < 2; ++u) {
                int c = (wid * 2 + u) * 16 + n;
                float a1c = a[c] * 1.442695041f;     // fold log2(e) into s1
                float a2c = a[128 + c] * 1.442695041f; // and s2
                #pragma unroll
                for (int r = 0; r < 4; ++r) {
                    p1[r] += acc[u][r] * a1c;
                    p2[r] += acc[u][r] * a2c;
                }
            }
            #pragma unroll
            for (int d = 1; d < 16; d <<= 1) {
                #pragma unroll
                for (int r = 0; r < 4; ++r) {
                    p1[r] += __shfl_xor(p1[r], d);
                    p2[r] += __shfl_xor(p2[r], d);
                }
            }
            if (n == 0) {
                #pragma unroll
                for (int r = 0; r < 4; ++r) {
                    sred[wid][0][q * 4 + r] = p1[r];
                    sred[wid][1][q * 4 + r] = p2[r];
                }
            }

            #pragma unroll
            for (int u = 0; u < 2; ++u)
                #pragma unroll
                for (int r = 0; r < 4; ++r)
                    tr[wid][u * 16 + n][q * 4 + r] = f2bf(acc[u][r]);
            __syncthreads();

            if (wid == 0 && lane < 16) {
                float v1 = 0.f, v2 = 0.f;
                #pragma unroll
                for (int v = 0; v < 4; ++v) { v1 += sred[v][0][lane]; v2 += sred[v][1][lane]; }
                s1g[rb + lane] = v1;
                s2g[rb + lane] = v2;
            }

            int jr = rb & 2047;
            int fl = lane & 31, jh = lane >> 5;
            bf16x8 v = *reinterpret_cast<const bf16x8*>(&tr[wid][fl][jh * 8]);
            int f = wid * 32 + fl;
            int t = f >> 4, nn = f & 15;
            int jc = jr >> 5;
            int qg = ((jr & 31) >> 3) + jh;          // jo>>3 for this 8-run
            *reinterpret_cast<bf16x8*>(
                whT + (size_t)(bb * 64 + jc) * 4096 + t * 512 + qg * 128 + nn * 8) = v;
        }
    }

    __threadfence();
    grid.sync();

    // =======================================================================
    // Phase 2: fused masked-softmax attention + PV (v16 structure: 2-slot
    // ring, ONE __syncthreads per chunk, no setprio, exp2 on pre-scaled
    // logits).
    // =======================================================================
    {
        char (*ring)[2][8192] = reinterpret_cast<char (*)[2][8192]>(smem);   // 32 KB
        uint32_t* mlds = reinterpret_cast<uint32_t*>(smem + 32768);          // 8.32 KB
        float* s2lds = reinterpret_cast<float*>(smem + 41088);               // 8 KB
        float (*dslds)[16] = reinterpret_cast<float (*)[16]>(smem + 49280);  // 256 B

        int rg = wid & 1, jh = wid >> 1;
        int b  = blockIdx.x & 7;                     // XCD-local batch
        int ib = (blockIdx.x >> 3) * 32;             // i-tile base (0..63)
        int row = ib + rg * 16 + n;

        float s1A = s1g[b * 2048 + row];
        const char* gbase = reinterpret_cast<const char*>(whT) + (size_t)b * 524288;

        // ---- stage masks: 32 rows x 64 dwords, pitch 65
        {
            int r = tid >> 3, sub = tid & 7;
            const uint4* src = reinterpret_cast<const uint4*>(
                adjb + (size_t)(ib + r) * 256 + sub * 32);
            uint4 v0 = src[0], v1 = src[1];
            uint32_t* dst = &mlds[r * 65 + sub * 8];
            dst[0] = v0.x; dst[1] = v0.y; dst[2] = v0.z; dst[3] = v0.w;
            dst[4] = v1.x; dst[5] = v1.y; dst[6] = v1.z; dst[7] = v1.w;
        }
        // ---- stage s2 (2048 floats)
        {
            const float* s2b = s2g + b * 2048;
            float4 v0 = *reinterpret_cast<const float4*>(s2b + tid * 8);
            float4 v1 = *reinterpret_cast<const float4*>(s2b + tid * 8 + 4);
            *reinterpret_cast<float4*>(&s2lds[tid * 8])     = v0;
            *reinterpret_cast<float4*>(&s2lds[tid * 8 + 4]) = v1;
        }

        // ---- prologue: each jh pair stages its chunk 0 (waves split 4 KB)
        {
            const char* g = gbase + (size_t)(jh * 32) * 8192 + rg * 4096 + lane * 16;
            char* l = &ring[jh][0][rg * 4096];
            #pragma unroll
            for (int i = 0; i < 4; ++i)
                gload_lds16(g + i * 1024, l + i * 1024);
        }
        __syncthreads();

        f32x4 acc[8] = {};
        float ds = 0.f;
        int mrow = (rg * 16 + n) * 65 + jh * 32;

        for (int c = 0; c < 32; ++c) {
            int cur = c & 1;
            if (c < 31) {                            // stage chunk c+1
                const char* g = gbase + (size_t)(jh * 32 + c + 1) * 8192
                                + rg * 4096 + lane * 16;
                char* l = &ring[jh][cur ^ 1][rg * 4096];
                #pragma unroll
                for (int i = 0; i < 4; ++i)
                    gload_lds16(g + i * 1024, l + i * 1024);
            }

            // ---- B frags from ring (lane*16 contiguous, conflict-free b128)
            const char* cb = &ring[jh][cur][0] + lane * 16;
            bf16x8 nb[8];
            #pragma unroll
            for (int t = 0; t < 8; ++t)
                nb[t] = *reinterpret_cast<const bf16x8*>(cb + t * 1024);

            // ---- mask + s2 from LDS (broadcast-friendly)
            uint32_t mA = mlds[mrow + c] >> (q * 8);
            int sb = (jh * 32 + c) * 32 + q * 8;
            float4 s2a = *reinterpret_cast<const float4*>(&s2lds[sb]);
            float4 s2c = *reinterpret_cast<const float4*>(&s2lds[sb + 4]);
            float s2arr[8] = {s2a.x, s2a.y, s2a.z, s2a.w,
                              s2c.x, s2c.y, s2c.z, s2c.w};

            // ---- P for chunk c (pre-scaled logits -> v_exp_f32 direct)
            float p[8];
            #pragma unroll
            for (int j = 0; j < 8; ++j) {
                float e = s1A + s2arr[j];
                e = fmaxf(e, ALPHA * e);
                float v = ((mA >> j) & 1) ? __builtin_amdgcn_exp2f(e) : 0.0f;
                ds += v; p[j] = v;
            }
            union { uint32_t u32[4]; bf16x8 v; } cv;
            #pragma unroll
            for (int pp = 0; pp < 4; ++pp)
                cv.u32[pp] = pk_bf16(p[2 * pp], p[2 * pp + 1]);

            #pragma unroll
            for (int t = 0; t < 8; ++t)
                acc[t] = __builtin_amdgcn_mfma_f32_16x16x32_bf16(cv.v, nb[t], acc[t], 0, 0, 0);

            __syncthreads();                         // slot rotate + stage done
        }

        // ---- intra-wave denominators
        ds += __shfl_xor(ds, 16); ds += __shfl_xor(ds, 32);
        if (q == 0) dslds[wid][n] = ds;

        // ---- 2-way combine across jh (reuse ring as 16 KB buffer)
        f32x4* cbuf = reinterpret_cast<f32x4*>(&ring[0][0][0]);
        __syncthreads();                             // ring reads done + dslds
        if (jh == 1) {
            #pragma unroll
            for (int i = 0; i < 8; ++i)
                cbuf[(rg * 8 + i) * 64 + lane] = acc[i];
        }
        __syncthreads();
        if (jh == 0) {
            #pragma unroll
            for (int i = 0; i < 8; ++i)
                acc[i] += cbuf[(rg * 8 + i) * 64 + lane];

            float dtot = dslds[rg][n] + dslds[2 + rg][n];
            float rd[4];
            #pragma unroll
            for (int r = 0; r < 4; ++r)
                rd[r] = 1.0f / __shfl(dtot, q * 4 + r);

            size_t ob = ((size_t)b * 2048 + ib + rg * 16) * 128;
            #pragma unroll
            for (int t = 0; t < 8; ++t)
                #pragma unroll
                for (int r = 0; r < 4; ++r)
                    out[ob + (size_t)(q * 4 + r) * 128 + t * 16 + n] = acc[t][r] * rd[r];
        }
    }
}

// ---------------------------------------------------------------------------
extern "C" void kernel_launch(void* const* d_in, const int* in_sizes, int n_in,
                              void* d_out, int out_size, void* d_ws, size_t ws_size,
                              hipStream_t stream) {
    const float* h   = (const float*)d_in[0];   // [8][2048][128] f32
    const int*   adj = (const int*)d_in[1];     // [2048][2048] i32
    const float* W   = (const float*)d_in[2];   // [128][128] f32
    const float* a   = (const float*)d_in[3];   // [256][1] f32
    float* out = (float*)d_out;                 // [8][2048][128] f32

    char* ws = (char*)d_ws;
    short* whT = (short*)ws;                                  // 4 MB  bf16 whT (chunk-tiled)
    float* s1  = (float*)(ws + 4194304);                      // 64 KB
    float* s2  = (float*)(ws + 4259840);                      // 64 KB
    uint8_t* bytes = (uint8_t*)(ws + 4325376);                // 512 KB
    short* WTg = (short*)(ws + 4849664);                      // 32 KB bf16 W^T

    void* args[] = { (void*)&h, (void*)&adj, (void*)&W, (void*)&a,
                     (void*)&whT, (void*)&s1, (void*)&s2, (void*)&bytes,
                     (void*)&WTg, (void*)&out };
    hipLaunchCooperativeKernel(reinterpret_cast<void*>(fused_kernel),
                               dim3(512), dim3(256), args, 0, stream);
}

// Round 7
// 105.582 us; speedup vs baseline: 2.8228x; 2.8228x over previous
//
#include <hip/hip_runtime.h>
#include <hip/hip_bf16.h>
#include <stdint.h>

#define ALPHA 0.2f

typedef __attribute__((ext_vector_type(8))) short bf16x8;
typedef __attribute__((ext_vector_type(4))) float f32x4;

__device__ __forceinline__ short f2bf(float f) {
    union { float f; uint32_t u; } c; c.f = f;
    uint32_t u = c.u + 0x7FFF + ((c.u >> 16) & 1);   // round-to-nearest-even
    return (short)(u >> 16);
}

// pack two fp32 -> packed bf16 pair (round-half-up)
__device__ __forceinline__ uint32_t pk_bf16(float lo, float hi) {
    union { float f; uint32_t u; } a, b;
    a.f = lo; b.f = hi;
    return __builtin_amdgcn_perm(b.u + 0x8000u, a.u + 0x8000u, 0x07060302u);
}

// ---------------------------------------------------------------------------
// Kernel 0: pack adj into byte-masks (8 ints -> 1 byte per thread). First 64
// blocks also pre-transpose W (fp32 [k][f]) -> WTg (bf16 [f][k]).
// ---------------------------------------------------------------------------
__global__ __launch_bounds__(256) void pack_adj_kernel(
        const int* __restrict__ adj, uint8_t* __restrict__ bytes,
        const float* __restrict__ W, short* __restrict__ WTg) {
    int t = blockIdx.x * 256 + threadIdx.x;            // 524288 threads
    const int4* a4 = reinterpret_cast<const int4*>(adj) + (size_t)t * 2;
    int4 x0 = a4[0], x1 = a4[1];
    uint32_t m = 0;
    m |= (x0.x > 0) ? 1u   : 0u;  m |= (x0.y > 0) ? 2u   : 0u;
    m |= (x0.z > 0) ? 4u   : 0u;  m |= (x0.w > 0) ? 8u   : 0u;
    m |= (x1.x > 0) ? 16u  : 0u;  m |= (x1.y > 0) ? 32u  : 0u;
    m |= (x1.z > 0) ? 64u  : 0u;  m |= (x1.w > 0) ? 128u : 0u;
    bytes[t] = (uint8_t)m;

    if (blockIdx.x < 64) {
        int idx = blockIdx.x * 256 + threadIdx.x;
        int k = idx >> 7, f = idx & 127;
        WTg[f * 128 + k] = f2bf(W[k * 128 + f]);
    }
}

// ---------------------------------------------------------------------------
// Kernel 1: Wh = h @ W; epilogue: s1/s2 and whT in MFMA-frag-ordered chunk
// layout. XCD swizzle: b = blockIdx & 7. Grid 1024 x 256 thr.
// s1/s2 pre-scaled by log2(e) so attn uses v_exp_f32 (exp2) directly.
// ---------------------------------------------------------------------------
__global__ __launch_bounds__(256) void wh_kernel(
        const float* __restrict__ h, const short* __restrict__ WTg,
        const float* __restrict__ a, short* __restrict__ whT,
        float* __restrict__ s1g, float* __restrict__ s2g) {
    __shared__ float sred[4][2][16];
    __shared__ short tr[4][32][24];

    int tid = threadIdx.x, wid = tid >> 6, lane = tid & 63;
    int q = lane >> 4, n = lane & 15;
    int bb = blockIdx.x & 7;                           // XCD-local batch
    int tile = blockIdx.x >> 3;                        // 0..127
    int rb = bb * 2048 + tile * 16;                    // global row base
    int row = rb + n;

    f32x4 acc[2] = {};
    #pragma unroll
    for (int kc = 0; kc < 4; ++kc) {
        const float* hp = h + (size_t)row * 128 + kc * 32 + q * 8;
        float4 h0 = reinterpret_cast<const float4*>(hp)[0];
        float4 h1 = reinterpret_cast<const float4*>(hp)[1];
        bf16x8 afrag;
        afrag[0] = f2bf(h0.x); afrag[1] = f2bf(h0.y);
        afrag[2] = f2bf(h0.z); afrag[3] = f2bf(h0.w);
        afrag[4] = f2bf(h1.x); afrag[5] = f2bf(h1.y);
        afrag[6] = f2bf(h1.z); afrag[7] = f2bf(h1.w);
        #pragma unroll
        for (int u = 0; u < 2; ++u) {
            int t = wid * 2 + u;
            bf16x8 bfrag = *reinterpret_cast<const bf16x8*>(
                WTg + (t * 16 + n) * 128 + kc * 32 + q * 8);
            acc[u] = __builtin_amdgcn_mfma_f32_16x16x32_bf16(afrag, bfrag, acc[u], 0, 0, 0);
        }
    }

    float p1[4] = {0.f, 0.f, 0.f, 0.f}, p2[4] = {0.f, 0.f, 0.f, 0.f};
    #pragma unroll
    for (int u = 0; u < 2; ++u) {
        int c = (wid * 2 + u) * 16 + n;
        float a1c = a[c] * 1.442695041f;               // fold log2(e) into s1
        float a2c = a[128 + c] * 1.442695041f;         // and s2
        #pragma unroll
        for (int r = 0; r < 4; ++r) {
            p1[r] += acc[u][r] * a1c;
            p2[r] += acc[u][r] * a2c;
        }
    }
    #pragma unroll
    for (int d = 1; d < 16; d <<= 1) {
        #pragma unroll
        for (int r = 0; r < 4; ++r) {
            p1[r] += __shfl_xor(p1[r], d);
            p2[r] += __shfl_xor(p2[r], d);
        }
    }
    if (n == 0) {
        #pragma unroll
        for (int r = 0; r < 4; ++r) {
            sred[wid][0][q * 4 + r] = p1[r];
            sred[wid][1][q * 4 + r] = p2[r];
        }
    }

    #pragma unroll
    for (int u = 0; u < 2; ++u)
        #pragma unroll
        for (int r = 0; r < 4; ++r)
            tr[wid][u * 16 + n][q * 4 + r] = f2bf(acc[u][r]);
    __syncthreads();

    if (wid == 0 && lane < 16) {
        float v1 = 0.f, v2 = 0.f;
        #pragma unroll
        for (int v = 0; v < 4; ++v) { v1 += sred[v][0][lane]; v2 += sred[v][1][lane]; }
        s1g[rb + lane] = v1;
        s2g[rb + lane] = v2;
    }

    int jr = rb & 2047;
    int fl = lane & 31, jh = lane >> 5;
    bf16x8 v = *reinterpret_cast<const bf16x8*>(&tr[wid][fl][jh * 8]);
    int f = wid * 32 + fl;
    int t = f >> 4, nn = f & 15;
    int jc = jr >> 5;
    int qg = ((jr & 31) >> 3) + jh;                    // jo>>3 for this 8-run
    *reinterpret_cast<bf16x8*>(
        whT + (size_t)(bb * 64 + jc) * 4096 + t * 512 + qg * 128 + nn * 8) = v;
}

// ---------------------------------------------------------------------------
// Kernel 2 (v17): direct-from-L2 B-fragments, NO LDS ring, NO barriers in
// the main loop. Rationale (from the fused run's counters + pipe budget):
// whT is L2-resident (512 KB slice/XCD); the v16 LDS ring moved 96 KB/iter/CU
// through the LDS pipe (~10 us) and forced a block-wide barrier + implicit
// vmcnt(0) drain every iteration. Here each wave loads its 8 bf16x8 B-frags
// straight to registers (ping-pong double buffer, loads for chunk c+1 issued
// before chunk c's MFMAs) and waves slip freely — the compiler counts vmcnt
// across iterations. Cost: 2x L2 read traffic (rg-waves no longer share);
// L1 absorbs part. Masks/s2 still staged to LDS once (one prologue barrier).
// ---------------------------------------------------------------------------
__device__ __forceinline__ void load_nb(const char* gb, int chunk, int lane,
                                        bf16x8* nb) {
    const char* cb = gb + (size_t)chunk * 8192 + lane * 16;
    #pragma unroll
    for (int t = 0; t < 8; ++t)
        nb[t] = *reinterpret_cast<const bf16x8*>(cb + t * 1024);
}

__global__ __launch_bounds__(256, 2) void attn_kernel(
        const short* __restrict__ whT, const float* __restrict__ s1g,
        const float* __restrict__ s2g, const uint8_t* __restrict__ adjb,
        float* __restrict__ out) {
    __shared__ uint32_t mlds[32 * 65];                 // 8.32 KB masks
    __shared__ float s2lds[2048];                      // 8 KB s2
    __shared__ float dslds[4][16];                     // per-wave denominators
    __shared__ f32x4 cbuf[1024];                       // 16 KB combine buffer

    int tid = threadIdx.x, wid = tid >> 6, lane = tid & 63;
    int q = lane >> 4, n = lane & 15;
    int rg = wid & 1, jh = wid >> 1;
    int b  = blockIdx.x & 7;                           // XCD-local batch
    int ib = (blockIdx.x >> 3) * 32;                   // i-tile base (0..63)
    int row = ib + rg * 16 + n;                        // this wave's row (m=n)

    float s1A = s1g[b * 2048 + row];
    const char* gbase = reinterpret_cast<const char*>(whT) + (size_t)b * 524288;

    // ---- stage masks: 32 rows x 64 dwords, pitch 65
    {
        int r = tid >> 3, sub = tid & 7;
        const uint4* src = reinterpret_cast<const uint4*>(
            adjb + (size_t)(ib + r) * 256 + sub * 32);
        uint4 v0 = src[0], v1 = src[1];
        uint32_t* dst = &mlds[r * 65 + sub * 8];
        dst[0] = v0.x; dst[1] = v0.y; dst[2] = v0.z; dst[3] = v0.w;
        dst[4] = v1.x; dst[5] = v1.y; dst[6] = v1.z; dst[7] = v1.w;
    }
    // ---- stage s2 (2048 floats)
    {
        const float* s2b = s2g + b * 2048;
        float4 v0 = *reinterpret_cast<const float4*>(s2b + tid * 8);
        float4 v1 = *reinterpret_cast<const float4*>(s2b + tid * 8 + 4);
        *reinterpret_cast<float4*>(&s2lds[tid * 8])     = v0;
        *reinterpret_cast<float4*>(&s2lds[tid * 8 + 4]) = v1;
    }
    __syncthreads();                                   // masks/s2 visible

    f32x4 acc[8] = {};
    float ds = 0.f;
    int mrow = (rg * 16 + n) * 65 + jh * 32;
    int cb0 = jh * 32;                                 // this wave's chunk base

    bf16x8 nbA[8], nbB[8];
    load_nb(gbase, cb0, lane, nbA);

    #pragma unroll 1
    for (int cc = 0; cc < 32; cc += 2) {
        // ---- issue chunk cc+1 loads before consuming chunk cc
        load_nb(gbase, cb0 + cc + 1, lane, nbB);

        // ---- chunk cc: softmax P + MFMA on nbA
        {
            int c = cc;
            uint32_t mA = mlds[mrow + c] >> (q * 8);
            int sb = (cb0 + c) * 32 + q * 8;
            float4 s2a = *reinterpret_cast<const float4*>(&s2lds[sb]);
            float4 s2c = *reinterpret_cast<const float4*>(&s2lds[sb + 4]);
            float s2arr[8] = {s2a.x, s2a.y, s2a.z, s2a.w,
                              s2c.x, s2c.y, s2c.z, s2c.w};
            float p[8];
            #pragma unroll
            for (int j = 0; j < 8; ++j) {
                float e = s1A + s2arr[j];
                e = fmaxf(e, ALPHA * e);
                float v = ((mA >> j) & 1) ? __builtin_amdgcn_exp2f(e) : 0.0f;
                ds += v; p[j] = v;
            }
            union { uint32_t u32[4]; bf16x8 v; } cv;
            #pragma unroll
            for (int pp = 0; pp < 4; ++pp)
                cv.u32[pp] = pk_bf16(p[2 * pp], p[2 * pp + 1]);
            #pragma unroll
            for (int t = 0; t < 8; ++t)
                acc[t] = __builtin_amdgcn_mfma_f32_16x16x32_bf16(cv.v, nbA[t], acc[t], 0, 0, 0);
        }

        // ---- issue chunk cc+2 loads before consuming chunk cc+1
        if (cc + 2 < 32) load_nb(gbase, cb0 + cc + 2, lane, nbA);

        // ---- chunk cc+1: softmax P + MFMA on nbB
        {
            int c = cc + 1;
            uint32_t mA = mlds[mrow + c] >> (q * 8);
            int sb = (cb0 + c) * 32 + q * 8;
            float4 s2a = *reinterpret_cast<const float4*>(&s2lds[sb]);
            float4 s2c = *reinterpret_cast<const float4*>(&s2lds[sb + 4]);
            float s2arr[8] = {s2a.x, s2a.y, s2a.z, s2a.w,
                              s2c.x, s2c.y, s2c.z, s2c.w};
            float p[8];
            #pragma unroll
            for (int j = 0; j < 8; ++j) {
                float e = s1A + s2arr[j];
                e = fmaxf(e, ALPHA * e);
                float v = ((mA >> j) & 1) ? __builtin_amdgcn_exp2f(e) : 0.0f;
                ds += v; p[j] = v;
            }
            union { uint32_t u32[4]; bf16x8 v; } cv;
            #pragma unroll
            for (int pp = 0; pp < 4; ++pp)
                cv.u32[pp] = pk_bf16(p[2 * pp], p[2 * pp + 1]);
            #pragma unroll
            for (int t = 0; t < 8; ++t)
                acc[t] = __builtin_amdgcn_mfma_f32_16x16x32_bf16(cv.v, nbB[t], acc[t], 0, 0, 0);
        }
    }

    // ---- intra-wave denominators (row m in lanes m, m+16, m+32, m+48)
    ds += __shfl_xor(ds, 16); ds += __shfl_xor(ds, 32);
    if (q == 0) dslds[wid][n] = ds;

    // ---- 2-way combine across jh
    __syncthreads();                                   // dslds + all waves done
    if (jh == 1) {
        #pragma unroll
        for (int i = 0; i < 8; ++i)
            cbuf[(rg * 8 + i) * 64 + lane] = acc[i];
    }
    __syncthreads();
    if (jh == 0) {
        #pragma unroll
        for (int i = 0; i < 8; ++i)
            acc[i] += cbuf[(rg * 8 + i) * 64 + lane];

        float dtot = dslds[rg][n] + dslds[2 + rg][n];
        float rd[4];
        #pragma unroll
        for (int r = 0; r < 4; ++r)
            rd[r] = 1.0f / __shfl(dtot, q * 4 + r);

        size_t ob = ((size_t)b * 2048 + ib + rg * 16) * 128;
        #pragma unroll
        for (int t = 0; t < 8; ++t)
            #pragma unroll
            for (int r = 0; r < 4; ++r)
                out[ob + (size_t)(q * 4 + r) * 128 + t * 16 + n] = acc[t][r] * rd[r];
    }
}

// ---------------------------------------------------------------------------
extern "C" void kernel_launch(void* const* d_in, const int* in_sizes, int n_in,
                              void* d_out, int out_size, void* d_ws, size_t ws_size,
                              hipStream_t stream) {
    const float* h   = (const float*)d_in[0];   // [8][2048][128] f32
    const int*   adj = (const int*)d_in[1];     // [2048][2048] i32
    const float* W   = (const float*)d_in[2];   // [128][128] f32
    const float* a   = (const float*)d_in[3];   // [256][1] f32
    float* out = (float*)d_out;                 // [8][2048][128] f32

    char* ws = (char*)d_ws;
    short* whT = (short*)ws;                                  // 4 MB  bf16 whT (chunk-tiled)
    float* s1  = (float*)(ws + 4194304);                      // 64 KB
    float* s2  = (float*)(ws + 4259840);                      // 64 KB
    uint8_t* bytes = (uint8_t*)(ws + 4325376);                // 512 KB
    short* WTg = (short*)(ws + 4849664);                      // 32 KB bf16 W^T

    pack_adj_kernel<<<2048, 256, 0, stream>>>(adj, bytes, W, WTg);
    wh_kernel<<<1024, 256, 0, stream>>>(h, WTg, a, whT, s1, s2);
    attn_kernel<<<512, 256, 0, stream>>>(whT, s1, s2, bytes, out);
}

// Round 8
// 104.341 us; speedup vs baseline: 2.8564x; 1.0119x over previous
//
#include <hip/hip_runtime.h>
#include <hip/hip_bf16.h>
#include <stdint.h>

#define ALPHA 0.2f

typedef __attribute__((ext_vector_type(8))) short bf16x8;
typedef __attribute__((ext_vector_type(4))) float f32x4;

__device__ __forceinline__ short f2bf(float f) {
    union { float f; uint32_t u; } c; c.f = f;
    uint32_t u = c.u + 0x7FFF + ((c.u >> 16) & 1);   // round-to-nearest-even
    return (short)(u >> 16);
}

// pack two fp32 -> packed bf16 pair (round-half-up)
__device__ __forceinline__ uint32_t pk_bf16(float lo, float hi) {
    union { float f; uint32_t u; } a, b;
    a.f = lo; b.f = hi;
    return __builtin_amdgcn_perm(b.u + 0x8000u, a.u + 0x8000u, 0x07060302u);
}

// ---------------------------------------------------------------------------
// Kernel 0: pack adj into byte-masks (8 ints -> 1 byte per thread). First 64
// blocks also pre-transpose W (fp32 [k][f]) -> WTg (bf16 [f][k]).
// ---------------------------------------------------------------------------
__global__ __launch_bounds__(256) void pack_adj_kernel(
        const int* __restrict__ adj, uint8_t* __restrict__ bytes,
        const float* __restrict__ W, short* __restrict__ WTg) {
    int t = blockIdx.x * 256 + threadIdx.x;            // 524288 threads
    const int4* a4 = reinterpret_cast<const int4*>(adj) + (size_t)t * 2;
    int4 x0 = a4[0], x1 = a4[1];
    uint32_t m = 0;
    m |= (x0.x > 0) ? 1u   : 0u;  m |= (x0.y > 0) ? 2u   : 0u;
    m |= (x0.z > 0) ? 4u   : 0u;  m |= (x0.w > 0) ? 8u   : 0u;
    m |= (x1.x > 0) ? 16u  : 0u;  m |= (x1.y > 0) ? 32u  : 0u;
    m |= (x1.z > 0) ? 64u  : 0u;  m |= (x1.w > 0) ? 128u : 0u;
    bytes[t] = (uint8_t)m;

    if (blockIdx.x < 64) {
        int idx = blockIdx.x * 256 + threadIdx.x;
        int k = idx >> 7, f = idx & 127;
        WTg[f * 128 + k] = f2bf(W[k * 128 + f]);
    }
}

// ---------------------------------------------------------------------------
// Kernel 1: Wh = h @ W; epilogue: s1/s2 and whT in MFMA-frag-ordered chunk
// layout. XCD swizzle: b = blockIdx & 7. Grid 1024 x 256 thr.
// s1/s2 pre-scaled by log2(e) so attn uses v_exp_f32 (exp2) directly.
// ---------------------------------------------------------------------------
__global__ __launch_bounds__(256) void wh_kernel(
        const float* __restrict__ h, const short* __restrict__ WTg,
        const float* __restrict__ a, short* __restrict__ whT,
        float* __restrict__ s1g, float* __restrict__ s2g) {
    __shared__ float sred[4][2][16];
    __shared__ short tr[4][32][24];

    int tid = threadIdx.x, wid = tid >> 6, lane = tid & 63;
    int q = lane >> 4, n = lane & 15;
    int bb = blockIdx.x & 7;                           // XCD-local batch
    int tile = blockIdx.x >> 3;                        // 0..127
    int rb = bb * 2048 + tile * 16;                    // global row base
    int row = rb + n;

    f32x4 acc[2] = {};
    #pragma unroll
    for (int kc = 0; kc < 4; ++kc) {
        const float* hp = h + (size_t)row * 128 + kc * 32 + q * 8;
        float4 h0 = reinterpret_cast<const float4*>(hp)[0];
        float4 h1 = reinterpret_cast<const float4*>(hp)[1];
        bf16x8 afrag;
        afrag[0] = f2bf(h0.x); afrag[1] = f2bf(h0.y);
        afrag[2] = f2bf(h0.z); afrag[3] = f2bf(h0.w);
        afrag[4] = f2bf(h1.x); afrag[5] = f2bf(h1.y);
        afrag[6] = f2bf(h1.z); afrag[7] = f2bf(h1.w);
        #pragma unroll
        for (int u = 0; u < 2; ++u) {
            int t = wid * 2 + u;
            bf16x8 bfrag = *reinterpret_cast<const bf16x8*>(
                WTg + (t * 16 + n) * 128 + kc * 32 + q * 8);
            acc[u] = __builtin_amdgcn_mfma_f32_16x16x32_bf16(afrag, bfrag, acc[u], 0, 0, 0);
        }
    }

    float p1[4] = {0.f, 0.f, 0.f, 0.f}, p2[4] = {0.f, 0.f, 0.f, 0.f};
    #pragma unroll
    for (int u = 0; u < 2; ++u) {
        int c = (wid * 2 + u) * 16 + n;
        float a1c = a[c] * 1.442695041f;               // fold log2(e) into s1
        float a2c = a[128 + c] * 1.442695041f;         // and s2
        #pragma unroll
        for (int r = 0; r < 4; ++r) {
            p1[r] += acc[u][r] * a1c;
            p2[r] += acc[u][r] * a2c;
        }
    }
    #pragma unroll
    for (int d = 1; d < 16; d <<= 1) {
        #pragma unroll
        for (int r = 0; r < 4; ++r) {
            p1[r] += __shfl_xor(p1[r], d);
            p2[r] += __shfl_xor(p2[r], d);
        }
    }
    if (n == 0) {
        #pragma unroll
        for (int r = 0; r < 4; ++r) {
            sred[wid][0][q * 4 + r] = p1[r];
            sred[wid][1][q * 4 + r] = p2[r];
        }
    }

    #pragma unroll
    for (int u = 0; u < 2; ++u)
        #pragma unroll
        for (int r = 0; r < 4; ++r)
            tr[wid][u * 16 + n][q * 4 + r] = f2bf(acc[u][r]);
    __syncthreads();

    if (wid == 0 && lane < 16) {
        float v1 = 0.f, v2 = 0.f;
        #pragma unroll
        for (int v = 0; v < 4; ++v) { v1 += sred[v][0][lane]; v2 += sred[v][1][lane]; }
        s1g[rb + lane] = v1;
        s2g[rb + lane] = v2;
    }

    int jr = rb & 2047;
    int fl = lane & 31, jh = lane >> 5;
    bf16x8 v = *reinterpret_cast<const bf16x8*>(&tr[wid][fl][jh * 8]);
    int f = wid * 32 + fl;
    int t = f >> 4, nn = f & 15;
    int jc = jr >> 5;
    int qg = ((jr & 31) >> 3) + jh;                    // jo>>3 for this 8-run
    *reinterpret_cast<bf16x8*>(
        whT + (size_t)(bb * 64 + jc) * 4096 + t * 512 + qg * 128 + nn * 8) = v;
}

// ---------------------------------------------------------------------------
// Kernel 2 (v18): direct-from-L2, dual-row-group waves, 4-way j-split.
// v17's two rg-waves read identical chunk streams (2x L2/VMEM amplification).
// Here each wave carries TWO A-fragments (rows ib+0..15 and ib+16..31)
// against the same B-fragments, and the 4 waves split j 4 ways (16 chunks
// each): block reads exactly the unique 512 KB, VMEM instr count halved,
// 2x compute per load for latency hiding. No barriers in the main loop.
// Epilogue: single-barrier 4-way combine (waves 1-3 dump acc to cbuf,
// wave 0 sums + normalizes + stores).
// ---------------------------------------------------------------------------
__device__ __forceinline__ void load_nb(const char* gb, int chunk, int lane,
                                        bf16x8* nb) {
    const char* cb = gb + (size_t)chunk * 8192 + lane * 16;
    #pragma unroll
    for (int t = 0; t < 8; ++t)
        nb[t] = *reinterpret_cast<const bf16x8*>(cb + t * 1024);
}

__global__ __launch_bounds__(256, 2) void attn_kernel(
        const short* __restrict__ whT, const float* __restrict__ s1g,
        const float* __restrict__ s2g, const uint8_t* __restrict__ adjb,
        float* __restrict__ out) {
    __shared__ uint32_t mlds[32 * 65];                 // 8.32 KB masks
    __shared__ float s2lds[2048];                      // 8 KB s2
    __shared__ float dslds[4][2][16];                  // per-wave denominators
    __shared__ f32x4 cbuf[3][16][64];                  // 48 KB combine buffer

    int tid = threadIdx.x, wid = tid >> 6, lane = tid & 63;
    int q = lane >> 4, n = lane & 15;
    int b  = blockIdx.x & 7;                           // XCD-local batch
    int ib = (blockIdx.x >> 3) * 32;                   // i-tile base (0..63)

    float s1A0 = s1g[b * 2048 + ib + n];               // row group 0 (rows 0-15)
    float s1A1 = s1g[b * 2048 + ib + 16 + n];          // row group 1 (rows 16-31)
    const char* gbase = reinterpret_cast<const char*>(whT) + (size_t)b * 524288;

    // ---- stage masks: 32 rows x 64 dwords, pitch 65
    {
        int r = tid >> 3, sub = tid & 7;
        const uint4* src = reinterpret_cast<const uint4*>(
            adjb + (size_t)(ib + r) * 256 + sub * 32);
        uint4 v0 = src[0], v1 = src[1];
        uint32_t* dst = &mlds[r * 65 + sub * 8];
        dst[0] = v0.x; dst[1] = v0.y; dst[2] = v0.z; dst[3] = v0.w;
        dst[4] = v1.x; dst[5] = v1.y; dst[6] = v1.z; dst[7] = v1.w;
    }
    // ---- stage s2 (2048 floats)
    {
        const float* s2b = s2g + b * 2048;
        float4 v0 = *reinterpret_cast<const float4*>(s2b + tid * 8);
        float4 v1 = *reinterpret_cast<const float4*>(s2b + tid * 8 + 4);
        *reinterpret_cast<float4*>(&s2lds[tid * 8])     = v0;
        *reinterpret_cast<float4*>(&s2lds[tid * 8 + 4]) = v1;
    }
    __syncthreads();                                   // masks/s2 visible

    f32x4 acc0[8] = {}, acc1[8] = {};
    float ds0 = 0.f, ds1 = 0.f;
    int gc0 = wid * 16;                                // this wave's chunk base
    int mrow0 = n * 65, mrow1 = (16 + n) * 65;

    bf16x8 nbA[8], nbB[8];
    load_nb(gbase, gc0, lane, nbA);

#define PROCESS(C, NB)                                                        \
    {                                                                         \
        int gc = gc0 + (C);                                                   \
        uint32_t mA0 = mlds[mrow0 + gc] >> (q * 8);                           \
        uint32_t mA1 = mlds[mrow1 + gc] >> (q * 8);                           \
        int sb = gc * 32 + q * 8;                                             \
        float4 s2a = *reinterpret_cast<const float4*>(&s2lds[sb]);            \
        float4 s2c = *reinterpret_cast<const float4*>(&s2lds[sb + 4]);        \
        float s2arr[8] = {s2a.x, s2a.y, s2a.z, s2a.w,                         \
                          s2c.x, s2c.y, s2c.z, s2c.w};                        \
        float p0[8], p1[8];                                                   \
        _Pragma("unroll")                                                     \
        for (int j = 0; j < 8; ++j) {                                         \
            float e0 = s1A0 + s2arr[j];                                       \
            e0 = fmaxf(e0, ALPHA * e0);                                       \
            float v0 = ((mA0 >> j) & 1) ? __builtin_amdgcn_exp2f(e0) : 0.0f;  \
            ds0 += v0; p0[j] = v0;                                            \
            float e1 = s1A1 + s2arr[j];                                       \
            e1 = fmaxf(e1, ALPHA * e1);                                       \
            float v1 = ((mA1 >> j) & 1) ? __builtin_amdgcn_exp2f(e1) : 0.0f;  \
            ds1 += v1; p1[j] = v1;                                            \
        }                                                                     \
        union { uint32_t u32[4]; bf16x8 v; } cv0, cv1;                        \
        _Pragma("unroll")                                                     \
        for (int pp = 0; pp < 4; ++pp) {                                      \
            cv0.u32[pp] = pk_bf16(p0[2 * pp], p0[2 * pp + 1]);                \
            cv1.u32[pp] = pk_bf16(p1[2 * pp], p1[2 * pp + 1]);                \
        }                                                                     \
        _Pragma("unroll")                                                     \
        for (int t = 0; t < 8; ++t) {                                         \
            acc0[t] = __builtin_amdgcn_mfma_f32_16x16x32_bf16(                \
                cv0.v, (NB)[t], acc0[t], 0, 0, 0);                            \
            acc1[t] = __builtin_amdgcn_mfma_f32_16x16x32_bf16(                \
                cv1.v, (NB)[t], acc1[t], 0, 0, 0);                            \
        }                                                                     \
    }

    #pragma unroll 1
    for (int cc = 0; cc < 16; cc += 2) {
        load_nb(gbase, gc0 + cc + 1, lane, nbB);       // prefetch odd chunk
        PROCESS(cc, nbA)
        if (cc + 2 < 16) load_nb(gbase, gc0 + cc + 2, lane, nbA);
        PROCESS(cc + 1, nbB)
    }
#undef PROCESS

    // ---- intra-wave denominators (sum over q; lane n holds full row-n part)
    ds0 += __shfl_xor(ds0, 16); ds0 += __shfl_xor(ds0, 32);
    ds1 += __shfl_xor(ds1, 16); ds1 += __shfl_xor(ds1, 32);
    if (q == 0) { dslds[wid][0][n] = ds0; dslds[wid][1][n] = ds1; }

    // ---- 4-way combine: waves 1-3 dump, wave 0 sums (ONE barrier)
    if (wid != 0) {
        #pragma unroll
        for (int t = 0; t < 8; ++t) {
            cbuf[wid - 1][t][lane]     = acc0[t];
            cbuf[wid - 1][8 + t][lane] = acc1[t];
        }
    }
    __syncthreads();
    if (wid == 0) {
        #pragma unroll
        for (int w = 0; w < 3; ++w)
            #pragma unroll
            for (int t = 0; t < 8; ++t) {
                acc0[t] += cbuf[w][t][lane];
                acc1[t] += cbuf[w][8 + t][lane];
            }

        float dtot0 = dslds[0][0][n] + dslds[1][0][n] + dslds[2][0][n] + dslds[3][0][n];
        float dtot1 = dslds[0][1][n] + dslds[1][1][n] + dslds[2][1][n] + dslds[3][1][n];
        float rd0[4], rd1[4];
        #pragma unroll
        for (int r = 0; r < 4; ++r) {
            rd0[r] = 1.0f / __shfl(dtot0, q * 4 + r);
            rd1[r] = 1.0f / __shfl(dtot1, q * 4 + r);
        }

        size_t ob = ((size_t)b * 2048 + ib) * 128;
        #pragma unroll
        for (int t = 0; t < 8; ++t)
            #pragma unroll
            for (int r = 0; r < 4; ++r) {
                out[ob + (size_t)(q * 4 + r) * 128 + t * 16 + n]        = acc0[t][r] * rd0[r];
                out[ob + (size_t)(16 + q * 4 + r) * 128 + t * 16 + n]   = acc1[t][r] * rd1[r];
            }
    }
}

// ---------------------------------------------------------------------------
extern "C" void kernel_launch(void* const* d_in, const int* in_sizes, int n_in,
                              void* d_out, int out_size, void* d_ws, size_t ws_size,
                              hipStream_t stream) {
    const float* h   = (const float*)d_in[0];   // [8][2048][128] f32
    const int*   adj = (const int*)d_in[1];     // [2048][2048] i32
    const float* W   = (const float*)d_in[2];   // [128][128] f32
    const float* a   = (const float*)d_in[3];   // [256][1] f32
    float* out = (float*)d_out;                 // [8][2048][128] f32

    char* ws = (char*)d_ws;
    short* whT = (short*)ws;                                  // 4 MB  bf16 whT (chunk-tiled)
    float* s1  = (float*)(ws + 4194304);                      // 64 KB
    float* s2  = (float*)(ws + 4259840);                      // 64 KB
    uint8_t* bytes = (uint8_t*)(ws + 4325376);                // 512 KB
    short* WTg = (short*)(ws + 4849664);                      // 32 KB bf16 W^T

    pack_adj_kernel<<<2048, 256, 0, stream>>>(adj, bytes, W, WTg);
    wh_kernel<<<1024, 256, 0, stream>>>(h, WTg, a, whT, s1, s2);
    attn_kernel<<<512, 256, 0, stream>>>(whT, s1, s2, bytes, out);
}